// Round 10
// baseline (1386.763 us; speedup 1.0000x reference)
//
#include <hip/hip_runtime.h>

// Problem constants (B, L_IN, D) = (4, 4096, 1024)
#define BB 4
#define LL 4096
#define DD 1024
#define SS 64   // number of chunks in the scan
#define TT 64   // chunk length (SS*TT == LL)
#define NCH 16  // chains: (DD/256) * BB

typedef __attribute__((ext_vector_type(4))) float  floatx4;
typedef __attribute__((ext_vector_type(8))) short  shortx8;
typedef __attribute__((ext_vector_type(8))) unsigned short ushortx8;

static __device__ __forceinline__ unsigned short f2bf(float f) {
    unsigned int u = __float_as_uint(f);
    u += 0x7fffu + ((u >> 16) & 1u);           // round-to-nearest-even
    return (unsigned short)(u >> 16);
}
static __device__ __forceinline__ float bf2f(unsigned short h) {
    return __uint_as_float(((unsigned int)h) << 16);
}

// ---------------- merged f32 -> bf16 cast (inputs + Wi + Wo-interleaved) ----
// Also zeroes the scan flag array (runs before GEMM1 -> visible by scan time).
#define NIN4 (BB * LL * DD / 4)          // 4194304
#define NWI4 (2 * DD * DD / 4)           // 524288
#define NWO8 (DD * DD / 4)               // 262144 (8 outputs/thread)
__global__ void cast_all_kernel(const float4* __restrict__ s_in, ushort4* __restrict__ d_inb,
                                const float4* __restrict__ s_wi, ushort4* __restrict__ d_wib,
                                const float* __restrict__ s_wo, unsigned short* __restrict__ d_wob,
                                int* __restrict__ flags) {
    int i = blockIdx.x * blockDim.x + threadIdx.x;
    if (i < NCH * SS) flags[i] = 0;
    if (i < NIN4 + NWI4) {
        const float4* s; ushort4* d; int j;
        if (i < NIN4) { s = s_in; d = d_inb; j = i; }
        else          { s = s_wi; d = d_wib; j = i - NIN4; }
        float4 v = s[j];
        ushort4 o;
        o.x = f2bf(v.x); o.y = f2bf(v.y); o.z = f2bf(v.z); o.w = f2bf(v.w);
        d[j] = o;
    } else {
        int j = i - NIN4 - NWI4;               // j < NWO8
        int n  = j >> 8;                       // row (DD/4 = 256 quads per row)
        int d0 = (j & 255) * 4;
        const float* rowp = s_wo + (size_t)n * (2 * DD);
        float4 re = *(const float4*)(rowp + d0);
        float4 im = *(const float4*)(rowp + DD + d0);
        ushortx8 o;
        o[0] = f2bf(re.x); o[1] = f2bf(im.x);
        o[2] = f2bf(re.y); o[3] = f2bf(im.y);
        o[4] = f2bf(re.z); o[5] = f2bf(im.z);
        o[6] = f2bf(re.w); o[7] = f2bf(im.w);
        *(ushortx8*)(d_wob + (size_t)n * (2 * DD) + 2 * d0) = o;
    }
}

// ---------------- bf16 GEMM: C[M,N] = A[M,K] * B[N,K]^T + bias ----------------
// (unchanged r2/r8 proven kernel; see hazard proof in earlier rounds)
template<int K, int NT, int EPI>
__global__ __launch_bounds__(512, 2)
void gemm256(const unsigned short* __restrict__ A,
             const unsigned short* __restrict__ B,
             const float* __restrict__ bias,
             void* __restrict__ Cp) {
    constexpr int N   = NT * 256;
    constexpr int NKT = K / 64;            // 16 or 32 here
    __shared__ __align__(16) short As[2][256 * 64];   // 64 KB
    __shared__ __align__(16) short Bs[2][256 * 64];   // 64 KB

    const int tid = threadIdx.x;
    const int blk = blockIdx.x;
    const int xcd = blk & 7;
    const int i2  = blk >> 3;
    const int tileM = ((i2 / NT) * 8 + xcd) * 256;
    const int tileN = (i2 % NT) * 256;

    const int lane   = tid & 63;
    const int wave   = tid >> 6;
    const int wave_m = wave >> 2;          // 0..1
    const int wave_n = wave & 3;           // 0..3
    const int r16    = lane & 15;
    const int quad   = lane >> 4;
    const int slotx  = r16 & 7;
    const int wmRow  = wave_m * 64 + r16;
    const int wnRow  = wave_n * 32 + r16;

    const int srow = tid >> 3;                         // 0..63
    const int scol = ((tid & 7) ^ (srow & 7)) * 8;     // pre-swizzled k offset (shorts)
    const int ldsChunkBase = (tid & ~63) * 8;          // shorts
    const size_t aOff = (size_t)(tileM + srow) * K + scol;
    const size_t bOff = (size_t)(tileN + srow) * K + scol;

    floatx4 acc[8][4] = {};
    shortx8 af[4][2], bf0v[2][2], bf1v[2][2];

#define GLL(SRC, DST) __builtin_amdgcn_global_load_lds( \
        (const __attribute__((address_space(1))) void*)(SRC), \
        (__attribute__((address_space(3))) void*)(DST), 16, 0, 0)
#define STAGE_A(BUF, H, KT) do { \
    GLL(A + aOff + (size_t)((H) * 128) * K + (KT) * 64,      &As[BUF][(H) * 8192 + ldsChunkBase]); \
    GLL(A + aOff + (size_t)((H) * 128 + 64) * K + (KT) * 64, &As[BUF][(H) * 8192 + 4096 + ldsChunkBase]); \
} while (0)
#define STAGE_B(BUF, H, KT) do { \
    GLL(B + bOff + (size_t)((H) * 128) * K + (KT) * 64,      &Bs[BUF][(H) * 8192 + ldsChunkBase]); \
    GLL(B + bOff + (size_t)((H) * 128 + 64) * K + (KT) * 64, &Bs[BUF][(H) * 8192 + 4096 + ldsChunkBase]); \
} while (0)
#define LOAD_A(BUF, MH) do { \
    _Pragma("unroll") for (int il = 0; il < 4; ++il) \
    _Pragma("unroll") for (int kk = 0; kk < 2; ++kk) \
        af[il][kk] = *(const shortx8*)&As[BUF][((MH) * 128 + wmRow + il * 16) * 64 + ((kk * 4 + quad) ^ slotx) * 8]; \
} while (0)
#define LOAD_B(BUF, NH, DST) do { \
    _Pragma("unroll") for (int jl = 0; jl < 2; ++jl) \
    _Pragma("unroll") for (int kk = 0; kk < 2; ++kk) \
        DST[jl][kk] = *(const shortx8*)&Bs[BUF][((NH) * 128 + wnRow + jl * 16) * 64 + ((kk * 4 + quad) ^ slotx) * 8]; \
} while (0)
#define MFMAQ(MH, NH, BF) do { \
    __builtin_amdgcn_s_setprio(1); \
    _Pragma("unroll") for (int kk = 0; kk < 2; ++kk) \
    _Pragma("unroll") for (int il = 0; il < 4; ++il) \
    _Pragma("unroll") for (int jl = 0; jl < 2; ++jl) \
        acc[(MH) * 4 + il][(NH) * 2 + jl] = __builtin_amdgcn_mfma_f32_16x16x32_bf16( \
            af[il][kk], BF[jl][kk], acc[(MH) * 4 + il][(NH) * 2 + jl], 0, 0, 0); \
    __builtin_amdgcn_s_setprio(0); \
} while (0)
#define BAR()  __builtin_amdgcn_s_barrier()
#define LGKM0() asm volatile("s_waitcnt lgkmcnt(0)" ::: "memory")

    // prologue: tile0 (A0,B0,B1,A1) + A0(1),B1(1),A1(1) = 14 GLLs
    STAGE_A(0, 0, 0);
    STAGE_B(0, 0, 0);
    STAGE_B(0, 1, 0);
    STAGE_A(0, 1, 0);
    STAGE_A(1, 0, 1);
    STAGE_B(1, 1, 1);
    STAGE_A(1, 1, 1);
    asm volatile("s_waitcnt vmcnt(6)" ::: "memory");   // tile0 landed; 6 in flight
    BAR();
    // pre-issue ph1(t=0) operands
    LOAD_A(0, 0);
    LOAD_B(0, 0, bf0v);

#pragma unroll 2
    for (int t = 0; t < NKT; ++t) {
        const int cb = t & 1;
        const int t1 = (t + 1 < NKT) ? t + 1 : NKT - 1;   // clamped tail: keeps
        const int t2 = (t + 2 < NKT) ? t + 2 : NKT - 1;   // vmcnt counts uniform
        // ---- phase 1: Q(0,0) ----
        BAR();
        LGKM0();
        STAGE_B(cb ^ 1, 0, t1);
        MFMAQ(0, 0, bf0v);
        LOAD_B(cb, 1, bf1v);           // read-ahead for ph2
        // ---- phase 2: Q(0,1) ----
        BAR();
        LGKM0();
        STAGE_A(cb, 0, t2);
        MFMAQ(0, 1, bf1v);
        LOAD_A(cb, 1);                 // read-ahead for ph3
        // ---- phase 3: Q(1,0) ----
        BAR();
        LGKM0();
        STAGE_B(cb, 1, t2);
        MFMAQ(1, 0, bf0v);
        // ---- phase 4: Q(1,1) ----
        asm volatile("s_waitcnt vmcnt(4)" ::: "memory");  // retires through B0(t+1)
        BAR();
        STAGE_A(cb, 1, t2);
        MFMAQ(1, 1, bf1v);
        LOAD_A(cb ^ 1, 0);             // read-ahead for next tile's ph1
        LOAD_B(cb ^ 1, 0, bf0v);
    }
    asm volatile("s_waitcnt vmcnt(0) lgkmcnt(0)" ::: "memory");  // drain tail

    // epilogue
#pragma unroll
    for (int i = 0; i < 8; ++i) {
        const int row0 = tileM + (i >> 2) * 128 + wave_m * 64 + (i & 3) * 16 + quad * 4;
#pragma unroll
        for (int j = 0; j < 4; ++j) {
            const int col = tileN + (j >> 1) * 128 + wave_n * 32 + (j & 1) * 16 + r16;
            const float bv = bias[col];
#pragma unroll
            for (int r = 0; r < 4; ++r) {
                float v = acc[i][j][r] + bv;
                if (EPI == 0) {
                    ((unsigned short*)Cp)[(size_t)(row0 + r) * N + col] = f2bf(v);
                } else {
                    ((float*)Cp)[(size_t)(row0 + r) * N + col] = fmaxf(v, 0.0f);
                }
            }
        }
    }
#undef GLL
#undef STAGE_A
#undef STAGE_B
#undef LOAD_A
#undef LOAD_B
#undef MFMAQ
#undef BAR
#undef LGKM0
}

// ---------------- ONE-PASS scan: decoupled flag-wait, LDS-hybrid chunk ------
// Grid (DD/256, SS, BB) = 1024 blocks x 256 thr, plain launch, UNCONDITIONAL.
// Deadlock-freedom by construction: __launch_bounds__(256,4) caps VGPR at 128,
// LDS 32 KB/block -> 4 blocks/CU co-resident (LDS 128<=160 KB, thr 1024<=2048)
// -> all 1024 blocks resident -> spin-wait safe under ANY dispatch order.
//
// Spill fix (r7/r8/r9 post-mortems): pure-register w[64] spilled 3x. Split the
// chunk: steps 0..31 in registers (w[32]), steps 32..63 in LDS [32][256]
// (thread-column-private -> no barriers; addr % 32 == tid % 32 -> 2-way bank
// aliasing = free). Live VGPRs ~60-70 << 128.
//
// Ordering (standard decoupled-lookback): publish payload (relaxed, agent) ->
// per-thread agent fence -> __syncthreads -> thread0 release-stores flag.
// Consumer: lane0-per-wave acquire-spins on flags (s_sleep between polls),
// then all lanes read payloads via relaxed agent-scope atomic loads (coherence
// point, safe across XCD L2s).
__global__ __launch_bounds__(256, 4)
void scan_onepass(const unsigned short* __restrict__ u,
                  const float* __restrict__ plog,
                  unsigned long long* __restrict__ Epub,
                  int* __restrict__ flags,
                  unsigned short* __restrict__ xr) {
    __shared__ unsigned int wl[32][256];               // 32 KB, column-private
    const int tid = threadIdx.x;
    const int d = blockIdx.x * 256 + tid;
    const int c = blockIdx.y, b = blockIdx.z;
    const int chain = b * (DD / 256) + blockIdx.x;     // 0..15

    // ---- load chunk: first 32 steps -> registers, last 32 -> LDS ----
    unsigned int w[32];
    {
        const unsigned short* up = u + (size_t)(b * LL + c * TT) * (2 * DD) + 2 * d;
#pragma unroll
        for (int tl = 0; tl < 32; ++tl) { w[tl] = *(const unsigned int*)up; up += 2 * DD; }
#pragma unroll
        for (int tl = 0; tl < 32; ++tl) { wl[tl][tid] = *(const unsigned int*)up; up += 2 * DD; }
    }
    const float v  = expf(plog[d]);
    const float th = expf(plog[DD + d]);
    const float a  = expf(-v);
    const float lr = a * cosf(th), li = a * sinf(th);

    // ---- phase A: local scan + publish ----
    {
        float zr = 0.f, zi = 0.f;
#pragma unroll
        for (int tl = 0; tl < 32; ++tl) {
            float xv = bf2f((unsigned short)(w[tl] & 0xffffu));
            float yv = bf2f((unsigned short)(w[tl] >> 16));
            float t = lr * zr - li * zi + xv;
            zi = lr * zi + li * zr + yv;
            zr = t;
        }
#pragma unroll 8
        for (int tl = 0; tl < 32; ++tl) {
            unsigned int q = wl[tl][tid];
            float xv = bf2f((unsigned short)(q & 0xffffu));
            float yv = bf2f((unsigned short)(q >> 16));
            float t = lr * zr - li * zi + xv;
            zi = lr * zi + li * zr + yv;
            zr = t;
        }
        unsigned long long q = (unsigned long long)__float_as_uint(zr) |
                               ((unsigned long long)__float_as_uint(zi) << 32);
        __hip_atomic_store(&Epub[(size_t)c * (BB * DD) + b * DD + d], q,
                           __ATOMIC_RELAXED, __HIP_MEMORY_SCOPE_AGENT);
    }
    __threadfence();
    __syncthreads();
    if (tid == 0)
        __hip_atomic_store(&flags[chain * SS + c], 1,
                           __ATOMIC_RELEASE, __HIP_MEMORY_SCOPE_AGENT);

    // ---- phase B: wait for predecessors, combine carry ----
    float yr = 0.f, yi = 0.f;
    if (c > 0) {
        const float aT = expf(-(float)TT * v);
        const float Lr = aT * cosf((float)TT * th), Li = aT * sinf((float)TT * th);
        const int fbase = chain * SS;
        if ((tid & 63) == 0) {                         // one spinner per wave
            for (int j0 = 0; j0 < c; j0 += 8) {
                for (;;) {
                    int got = 0;
#pragma unroll
                    for (int k = 0; k < 8; ++k) {
                        got += (j0 + k >= c) ? 1 :
                            (__hip_atomic_load(&flags[fbase + j0 + k],
                                 __ATOMIC_ACQUIRE, __HIP_MEMORY_SCOPE_AGENT) != 0);
                    }
                    if (got == 8) break;
                    __builtin_amdgcn_s_sleep(2);
                }
            }
        }
        const size_t pbase = (size_t)b * DD + d;
#define PLD(JJ) __hip_atomic_load(&Epub[(size_t)(JJ) * (BB * DD) + pbase], \
                                  __ATOMIC_RELAXED, __HIP_MEMORY_SCOPE_AGENT)
#define COMB(Q) do { \
        float er = __uint_as_float((unsigned int)(Q)); \
        float ei = __uint_as_float((unsigned int)((Q) >> 32)); \
        float t = Lr * yr - Li * yi + er; \
        yi = Lr * yi + Li * yr + ei; \
        yr = t; } while (0)
        int j = 0;
        for (; j + 4 <= c; j += 4) {                   // 4-wide: trims live regs
            unsigned long long q0 = PLD(j + 0), q1 = PLD(j + 1);
            unsigned long long q2 = PLD(j + 2), q3 = PLD(j + 3);
            COMB(q0); COMB(q1); COMB(q2); COMB(q3);
        }
        for (; j < c; ++j) { unsigned long long q = PLD(j); COMB(q); }
#undef PLD
#undef COMB
    }

    // ---- phase C: rescan (regs then LDS) with carry, store packed (re,im) ----
    {
        const float g = expf(plog[2 * DD + d]);
        unsigned short* xp = xr + (size_t)(b * LL + c * TT) * (2 * DD) + 2 * d;
#pragma unroll
        for (int tl = 0; tl < 32; ++tl) {
            float xv = bf2f((unsigned short)(w[tl] & 0xffffu));
            float yv = bf2f((unsigned short)(w[tl] >> 16));
            float t = lr * yr - li * yi + xv;
            yi = lr * yi + li * yr + yv;
            yr = t;
            *(unsigned int*)xp = (unsigned int)f2bf(g * yr) |
                                 ((unsigned int)f2bf(g * yi) << 16);
            xp += 2 * DD;
        }
#pragma unroll 8
        for (int tl = 0; tl < 32; ++tl) {
            unsigned int q = wl[tl][tid];
            float xv = bf2f((unsigned short)(q & 0xffffu));
            float yv = bf2f((unsigned short)(q >> 16));
            float t = lr * yr - li * yi + xv;
            yi = lr * yi + li * yr + yv;
            yr = t;
            *(unsigned int*)xp = (unsigned int)f2bf(g * yr) |
                                 ((unsigned int)f2bf(g * yi) << 16);
            xp += 2 * DD;
        }
    }
}

extern "C" void kernel_launch(void* const* d_in, const int* in_sizes, int n_in,
                              void* d_out, int out_size, void* d_ws, size_t ws_size,
                              hipStream_t stream) {
    const float* inputs = (const float*)d_in[0];   // B*L*D = 16777216
    const float* Wi     = (const float*)d_in[1];   // 2D*D  = 2097152
    const float* bi     = (const float*)d_in[2];   // 2D
    const float* Wo     = (const float*)d_in[3];   // D*2D  = 2097152
    const float* bo     = (const float*)d_in[4];   // D
    const float* plog   = (const float*)d_in[5];   // 3*D
    float* out = (float*)d_out;

    const size_t M = (size_t)BB * LL;              // 16384
    unsigned short* u_bf  = (unsigned short*)d_ws;             // M*2D bf16  (64 MB)
    unsigned short* xr_bf = u_bf  + M * 2 * DD;                // M*2D bf16  (64 MB)
    unsigned short* in_bf = xr_bf + M * 2 * DD;                // M*D  bf16  (32 MB)
    unsigned short* Wi_bf = in_bf + M * DD;                    // 2D*D bf16  (4 MB)
    unsigned short* Wo_bf = Wi_bf + (size_t)2 * DD * DD;       // D*2D bf16  (4 MB)
    // Epub (SS*B*D x8B = 2 MB) aliases in_bf (dead after GEMM1 completes;
    // scan_onepass, the first Epub writer, runs after GEMM1).
    unsigned long long* Epub = (unsigned long long*)in_bf;
    // flags (NCH*SS ints = 4 KB) after Wo_bf.
    int* flags = (int*)(Wo_bf + (size_t)2 * DD * DD);

    // merged bf16 casts (+ flag zeroing) in one dispatch
    {
        int total = NIN4 + NWI4 + NWO8;            // 4980736, divisible by 256
        cast_all_kernel<<<total / 256, 256, 0, stream>>>(
            (const float4*)inputs, (ushort4*)in_bf,
            (const float4*)Wi,     (ushort4*)Wi_bf,
            Wo,                    Wo_bf,
            flags);
    }

    // GEMM1: u[M, 2D] = in_bf[M, D] @ Wi^T + bi   (bf16 out), N=2048 -> NT=8
    gemm256<DD, 8, 0><<<(M / 256) * 8, 512, 0, stream>>>(
        in_bf, Wi_bf, bi, (void*)u_bf);

    // one-pass scan (u read ONCE; decoupled flag-wait; co-residency by
    // construction -> safe under any dispatch order)
    scan_onepass<<<dim3(DD / 256, SS, BB), 256, 0, stream>>>(
        u_bf, plog, Epub, flags, xr_bf);

    // GEMM2: out[M, D] = relu(xr[M, 2D] @ WoP^T + bo)  (f32 out), N=1024 -> NT=4
    gemm256<2 * DD, 4, 1><<<(M / 256) * 4, 512, 0, stream>>>(
        xr_bf, Wo_bf, bo, (void*)out);
}

// Round 11
// 294.994 us; speedup vs baseline: 4.7010x; 4.7010x over previous
//
#include <hip/hip_runtime.h>

// Problem constants (B, L_IN, D) = (4, 4096, 1024)
#define BB 4
#define LL 4096
#define DD 1024
#define SS 64   // number of chunks in the scan
#define TT 64   // chunk length (SS*TT == LL)
#define NCH 16  // chains: (DD/256) * BB

typedef __attribute__((ext_vector_type(4))) float  floatx4;
typedef __attribute__((ext_vector_type(8))) short  shortx8;
typedef __attribute__((ext_vector_type(8))) unsigned short ushortx8;

static __device__ __forceinline__ unsigned short f2bf(float f) {
    unsigned int u = __float_as_uint(f);
    u += 0x7fffu + ((u >> 16) & 1u);           // round-to-nearest-even
    return (unsigned short)(u >> 16);
}
static __device__ __forceinline__ float bf2f(unsigned short h) {
    return __uint_as_float(((unsigned int)h) << 16);
}

// ---------------- merged f32 -> bf16 cast (inputs + Wi + Wo-interleaved) ----
// Also zeroes the scan flag array (runs before GEMM1 -> visible by scan time).
#define NIN4 (BB * LL * DD / 4)          // 4194304
#define NWI4 (2 * DD * DD / 4)           // 524288
#define NWO8 (DD * DD / 4)               // 262144 (8 outputs/thread)
__global__ void cast_all_kernel(const float4* __restrict__ s_in, ushort4* __restrict__ d_inb,
                                const float4* __restrict__ s_wi, ushort4* __restrict__ d_wib,
                                const float* __restrict__ s_wo, unsigned short* __restrict__ d_wob,
                                int* __restrict__ flags) {
    int i = blockIdx.x * blockDim.x + threadIdx.x;
    if (i < NCH * SS)
        __hip_atomic_store(&flags[i], 0, __ATOMIC_RELAXED, __HIP_MEMORY_SCOPE_AGENT);
    if (i < NIN4 + NWI4) {
        const float4* s; ushort4* d; int j;
        if (i < NIN4) { s = s_in; d = d_inb; j = i; }
        else          { s = s_wi; d = d_wib; j = i - NIN4; }
        float4 v = s[j];
        ushort4 o;
        o.x = f2bf(v.x); o.y = f2bf(v.y); o.z = f2bf(v.z); o.w = f2bf(v.w);
        d[j] = o;
    } else {
        int j = i - NIN4 - NWI4;               // j < NWO8
        int n  = j >> 8;                       // row (DD/4 = 256 quads per row)
        int d0 = (j & 255) * 4;
        const float* rowp = s_wo + (size_t)n * (2 * DD);
        float4 re = *(const float4*)(rowp + d0);
        float4 im = *(const float4*)(rowp + DD + d0);
        ushortx8 o;
        o[0] = f2bf(re.x); o[1] = f2bf(im.x);
        o[2] = f2bf(re.y); o[3] = f2bf(im.y);
        o[4] = f2bf(re.z); o[5] = f2bf(im.z);
        o[6] = f2bf(re.w); o[7] = f2bf(im.w);
        *(ushortx8*)(d_wob + (size_t)n * (2 * DD) + 2 * d0) = o;
    }
}

// ---------------- bf16 GEMM: C[M,N] = A[M,K] * B[N,K]^T + bias ----------------
// (unchanged r2/r8 proven kernel; see hazard proof in earlier rounds)
template<int K, int NT, int EPI>
__global__ __launch_bounds__(512, 2)
void gemm256(const unsigned short* __restrict__ A,
             const unsigned short* __restrict__ B,
             const float* __restrict__ bias,
             void* __restrict__ Cp) {
    constexpr int N   = NT * 256;
    constexpr int NKT = K / 64;            // 16 or 32 here
    __shared__ __align__(16) short As[2][256 * 64];   // 64 KB
    __shared__ __align__(16) short Bs[2][256 * 64];   // 64 KB

    const int tid = threadIdx.x;
    const int blk = blockIdx.x;
    const int xcd = blk & 7;
    const int i2  = blk >> 3;
    const int tileM = ((i2 / NT) * 8 + xcd) * 256;
    const int tileN = (i2 % NT) * 256;

    const int lane   = tid & 63;
    const int wave   = tid >> 6;
    const int wave_m = wave >> 2;          // 0..1
    const int wave_n = wave & 3;           // 0..3
    const int r16    = lane & 15;
    const int quad   = lane >> 4;
    const int slotx  = r16 & 7;
    const int wmRow  = wave_m * 64 + r16;
    const int wnRow  = wave_n * 32 + r16;

    const int srow = tid >> 3;                         // 0..63
    const int scol = ((tid & 7) ^ (srow & 7)) * 8;     // pre-swizzled k offset (shorts)
    const int ldsChunkBase = (tid & ~63) * 8;          // shorts
    const size_t aOff = (size_t)(tileM + srow) * K + scol;
    const size_t bOff = (size_t)(tileN + srow) * K + scol;

    floatx4 acc[8][4] = {};
    shortx8 af[4][2], bf0v[2][2], bf1v[2][2];

#define GLL(SRC, DST) __builtin_amdgcn_global_load_lds( \
        (const __attribute__((address_space(1))) void*)(SRC), \
        (__attribute__((address_space(3))) void*)(DST), 16, 0, 0)
#define STAGE_A(BUF, H, KT) do { \
    GLL(A + aOff + (size_t)((H) * 128) * K + (KT) * 64,      &As[BUF][(H) * 8192 + ldsChunkBase]); \
    GLL(A + aOff + (size_t)((H) * 128 + 64) * K + (KT) * 64, &As[BUF][(H) * 8192 + 4096 + ldsChunkBase]); \
} while (0)
#define STAGE_B(BUF, H, KT) do { \
    GLL(B + bOff + (size_t)((H) * 128) * K + (KT) * 64,      &Bs[BUF][(H) * 8192 + ldsChunkBase]); \
    GLL(B + bOff + (size_t)((H) * 128 + 64) * K + (KT) * 64, &Bs[BUF][(H) * 8192 + 4096 + ldsChunkBase]); \
} while (0)
#define LOAD_A(BUF, MH) do { \
    _Pragma("unroll") for (int il = 0; il < 4; ++il) \
    _Pragma("unroll") for (int kk = 0; kk < 2; ++kk) \
        af[il][kk] = *(const shortx8*)&As[BUF][((MH) * 128 + wmRow + il * 16) * 64 + ((kk * 4 + quad) ^ slotx) * 8]; \
} while (0)
#define LOAD_B(BUF, NH, DST) do { \
    _Pragma("unroll") for (int jl = 0; jl < 2; ++jl) \
    _Pragma("unroll") for (int kk = 0; kk < 2; ++kk) \
        DST[jl][kk] = *(const shortx8*)&Bs[BUF][((NH) * 128 + wnRow + jl * 16) * 64 + ((kk * 4 + quad) ^ slotx) * 8]; \
} while (0)
#define MFMAQ(MH, NH, BF) do { \
    __builtin_amdgcn_s_setprio(1); \
    _Pragma("unroll") for (int kk = 0; kk < 2; ++kk) \
    _Pragma("unroll") for (int il = 0; il < 4; ++il) \
    _Pragma("unroll") for (int jl = 0; jl < 2; ++jl) \
        acc[(MH) * 4 + il][(NH) * 2 + jl] = __builtin_amdgcn_mfma_f32_16x16x32_bf16( \
            af[il][kk], BF[jl][kk], acc[(MH) * 4 + il][(NH) * 2 + jl], 0, 0, 0); \
    __builtin_amdgcn_s_setprio(0); \
} while (0)
#define BAR()  __builtin_amdgcn_s_barrier()
#define LGKM0() asm volatile("s_waitcnt lgkmcnt(0)" ::: "memory")

    // prologue: tile0 (A0,B0,B1,A1) + A0(1),B1(1),A1(1) = 14 GLLs
    STAGE_A(0, 0, 0);
    STAGE_B(0, 0, 0);
    STAGE_B(0, 1, 0);
    STAGE_A(0, 1, 0);
    STAGE_A(1, 0, 1);
    STAGE_B(1, 1, 1);
    STAGE_A(1, 1, 1);
    asm volatile("s_waitcnt vmcnt(6)" ::: "memory");   // tile0 landed; 6 in flight
    BAR();
    // pre-issue ph1(t=0) operands
    LOAD_A(0, 0);
    LOAD_B(0, 0, bf0v);

#pragma unroll 2
    for (int t = 0; t < NKT; ++t) {
        const int cb = t & 1;
        const int t1 = (t + 1 < NKT) ? t + 1 : NKT - 1;   // clamped tail: keeps
        const int t2 = (t + 2 < NKT) ? t + 2 : NKT - 1;   // vmcnt counts uniform
        // ---- phase 1: Q(0,0) ----
        BAR();
        LGKM0();
        STAGE_B(cb ^ 1, 0, t1);
        MFMAQ(0, 0, bf0v);
        LOAD_B(cb, 1, bf1v);           // read-ahead for ph2
        // ---- phase 2: Q(0,1) ----
        BAR();
        LGKM0();
        STAGE_A(cb, 0, t2);
        MFMAQ(0, 1, bf1v);
        LOAD_A(cb, 1);                 // read-ahead for ph3
        // ---- phase 3: Q(1,0) ----
        BAR();
        LGKM0();
        STAGE_B(cb, 1, t2);
        MFMAQ(1, 0, bf0v);
        // ---- phase 4: Q(1,1) ----
        asm volatile("s_waitcnt vmcnt(4)" ::: "memory");  // retires through B0(t+1)
        BAR();
        STAGE_A(cb, 1, t2);
        MFMAQ(1, 1, bf1v);
        LOAD_A(cb ^ 1, 0);             // read-ahead for next tile's ph1
        LOAD_B(cb ^ 1, 0, bf0v);
    }
    asm volatile("s_waitcnt vmcnt(0) lgkmcnt(0)" ::: "memory");  // drain tail

    // epilogue
#pragma unroll
    for (int i = 0; i < 8; ++i) {
        const int row0 = tileM + (i >> 2) * 128 + wave_m * 64 + (i & 3) * 16 + quad * 4;
#pragma unroll
        for (int j = 0; j < 4; ++j) {
            const int col = tileN + (j >> 1) * 128 + wave_n * 32 + (j & 1) * 16 + r16;
            const float bv = bias[col];
#pragma unroll
            for (int r = 0; r < 4; ++r) {
                float v = acc[i][j][r] + bv;
                if (EPI == 0) {
                    ((unsigned short*)Cp)[(size_t)(row0 + r) * N + col] = f2bf(v);
                } else {
                    ((float*)Cp)[(size_t)(row0 + r) * N + col] = fmaxf(v, 0.0f);
                }
            }
        }
    }
#undef GLL
#undef STAGE_A
#undef STAGE_B
#undef LOAD_A
#undef LOAD_B
#undef MFMAQ
#undef BAR
#undef LGKM0
}

// ---------------- ONE-PASS scan: decoupled flag-wait, LDS-hybrid chunk ------
// Grid (DD/256, SS, BB) = 1024 blocks x 256 thr, plain launch.
// Co-residency by construction (32 KB LDS, VGPR<=128, 256 thr -> >=4 blocks/CU
// -> all 1024 resident) -> flag-wait is deadlock-free under any dispatch order.
// r10 confirmed: runs, no spill (VGPR 52). r10's 1213 us came from the atomic
// DISCIPLINE: agent-scope ACQUIRE polls emit buffer_inv (L1/L2 invalidate) per
// iteration -> continuous L2 wipe device-wide -> 87 GB/s crawl.
//
// r11 fix — RELAXED write-through protocol (CUB decoupled-lookback style):
// relaxed agent atomics compile to global_load/store sc1 (bypass L1/L2,
// coherence point = Infinity Cache) with NO invalidate/writeback side-effects.
// Ordering enforced explicitly:
//   producer: payload stores (relaxed,sc1) -> s_waitcnt vmcnt(0) (payloads
//   ack'd at IC) -> __syncthreads (all waves) -> tid0 flag store (relaxed,sc1)
//   consumer: tid0 spin on flags (relaxed,sc1 loads, no inv) -> __syncthreads
//   -> all lanes payload loads (relaxed,sc1 -> read IC, see published data).
__global__ __launch_bounds__(256, 4)
void scan_onepass(const unsigned short* __restrict__ u,
                  const float* __restrict__ plog,
                  unsigned long long* __restrict__ Epub,
                  int* __restrict__ flags,
                  unsigned short* __restrict__ xr) {
    __shared__ unsigned int wl[32][256];               // 32 KB, column-private
    const int tid = threadIdx.x;
    const int d = blockIdx.x * 256 + tid;
    const int c = blockIdx.y, b = blockIdx.z;
    const int chain = b * (DD / 256) + blockIdx.x;     // 0..15

    // ---- load chunk: first 32 steps -> registers, last 32 -> LDS ----
    unsigned int w[32];
    {
        const unsigned short* up = u + (size_t)(b * LL + c * TT) * (2 * DD) + 2 * d;
#pragma unroll
        for (int tl = 0; tl < 32; ++tl) { w[tl] = *(const unsigned int*)up; up += 2 * DD; }
#pragma unroll
        for (int tl = 0; tl < 32; ++tl) { wl[tl][tid] = *(const unsigned int*)up; up += 2 * DD; }
    }
    const float v  = expf(plog[d]);
    const float th = expf(plog[DD + d]);
    const float a  = expf(-v);
    const float lr = a * cosf(th), li = a * sinf(th);

    // ---- phase A: local scan + publish (relaxed write-through) ----
    {
        float zr = 0.f, zi = 0.f;
#pragma unroll
        for (int tl = 0; tl < 32; ++tl) {
            float xv = bf2f((unsigned short)(w[tl] & 0xffffu));
            float yv = bf2f((unsigned short)(w[tl] >> 16));
            float t = lr * zr - li * zi + xv;
            zi = lr * zi + li * zr + yv;
            zr = t;
        }
#pragma unroll 8
        for (int tl = 0; tl < 32; ++tl) {
            unsigned int q = wl[tl][tid];
            float xv = bf2f((unsigned short)(q & 0xffffu));
            float yv = bf2f((unsigned short)(q >> 16));
            float t = lr * zr - li * zi + xv;
            zi = lr * zi + li * zr + yv;
            zr = t;
        }
        unsigned long long q = (unsigned long long)__float_as_uint(zr) |
                               ((unsigned long long)__float_as_uint(zi) << 32);
        __hip_atomic_store(&Epub[(size_t)c * (BB * DD) + b * DD + d], q,
                           __ATOMIC_RELAXED, __HIP_MEMORY_SCOPE_AGENT);
    }
    asm volatile("s_waitcnt vmcnt(0)" ::: "memory");   // payload ack'd at IC
    __syncthreads();                                    // all waves published
    if (tid == 0)
        __hip_atomic_store(&flags[chain * SS + c], 1,
                           __ATOMIC_RELAXED, __HIP_MEMORY_SCOPE_AGENT);

    // ---- phase B: wait for predecessors (relaxed polls), combine carry ----
    float yr = 0.f, yi = 0.f;
    if (c > 0) {
        const float aT = expf(-(float)TT * v);
        const float Lr = aT * cosf((float)TT * th), Li = aT * sinf((float)TT * th);
        const int fbase = chain * SS;
        if (tid == 0) {                                // one spinner per block
            for (int j0 = 0; j0 < c; j0 += 8) {
                for (;;) {
                    int got = 0;
#pragma unroll
                    for (int k = 0; k < 8; ++k) {
                        got += (j0 + k >= c) ? 1 :
                            (__hip_atomic_load(&flags[fbase + j0 + k],
                                 __ATOMIC_RELAXED, __HIP_MEMORY_SCOPE_AGENT) != 0);
                    }
                    if (got == 8) break;
                    __builtin_amdgcn_s_sleep(8);
                }
            }
        }
        __syncthreads();                               // spinner releases block
        const size_t pbase = (size_t)b * DD + d;
#define PLD(JJ) __hip_atomic_load(&Epub[(size_t)(JJ) * (BB * DD) + pbase], \
                                  __ATOMIC_RELAXED, __HIP_MEMORY_SCOPE_AGENT)
#define COMB(Q) do { \
        float er = __uint_as_float((unsigned int)(Q)); \
        float ei = __uint_as_float((unsigned int)((Q) >> 32)); \
        float t = Lr * yr - Li * yi + er; \
        yi = Lr * yi + Li * yr + ei; \
        yr = t; } while (0)
        int j = 0;
        for (; j + 4 <= c; j += 4) {                   // 4-wide: trims live regs
            unsigned long long q0 = PLD(j + 0), q1 = PLD(j + 1);
            unsigned long long q2 = PLD(j + 2), q3 = PLD(j + 3);
            COMB(q0); COMB(q1); COMB(q2); COMB(q3);
        }
        for (; j < c; ++j) { unsigned long long q = PLD(j); COMB(q); }
#undef PLD
#undef COMB
    }

    // ---- phase C: rescan (regs then LDS) with carry, store packed (re,im) ----
    {
        const float g = expf(plog[2 * DD + d]);
        unsigned short* xp = xr + (size_t)(b * LL + c * TT) * (2 * DD) + 2 * d;
#pragma unroll
        for (int tl = 0; tl < 32; ++tl) {
            float xv = bf2f((unsigned short)(w[tl] & 0xffffu));
            float yv = bf2f((unsigned short)(w[tl] >> 16));
            float t = lr * yr - li * yi + xv;
            yi = lr * yi + li * yr + yv;
            yr = t;
            *(unsigned int*)xp = (unsigned int)f2bf(g * yr) |
                                 ((unsigned int)f2bf(g * yi) << 16);
            xp += 2 * DD;
        }
#pragma unroll 8
        for (int tl = 0; tl < 32; ++tl) {
            unsigned int q = wl[tl][tid];
            float xv = bf2f((unsigned short)(q & 0xffffu));
            float yv = bf2f((unsigned short)(q >> 16));
            float t = lr * yr - li * yi + xv;
            yi = lr * yi + li * yr + yv;
            yr = t;
            *(unsigned int*)xp = (unsigned int)f2bf(g * yr) |
                                 ((unsigned int)f2bf(g * yi) << 16);
            xp += 2 * DD;
        }
    }
}

extern "C" void kernel_launch(void* const* d_in, const int* in_sizes, int n_in,
                              void* d_out, int out_size, void* d_ws, size_t ws_size,
                              hipStream_t stream) {
    const float* inputs = (const float*)d_in[0];   // B*L*D = 16777216
    const float* Wi     = (const float*)d_in[1];   // 2D*D  = 2097152
    const float* bi     = (const float*)d_in[2];   // 2D
    const float* Wo     = (const float*)d_in[3];   // D*2D  = 2097152
    const float* bo     = (const float*)d_in[4];   // D
    const float* plog   = (const float*)d_in[5];   // 3*D
    float* out = (float*)d_out;

    const size_t M = (size_t)BB * LL;              // 16384
    unsigned short* u_bf  = (unsigned short*)d_ws;             // M*2D bf16  (64 MB)
    unsigned short* xr_bf = u_bf  + M * 2 * DD;                // M*2D bf16  (64 MB)
    unsigned short* in_bf = xr_bf + M * 2 * DD;                // M*D  bf16  (32 MB)
    unsigned short* Wi_bf = in_bf + M * DD;                    // 2D*D bf16  (4 MB)
    unsigned short* Wo_bf = Wi_bf + (size_t)2 * DD * DD;       // D*2D bf16  (4 MB)
    // Epub (SS*B*D x8B = 2 MB) aliases in_bf (dead after GEMM1 completes;
    // scan_onepass, the first Epub writer, runs after GEMM1).
    unsigned long long* Epub = (unsigned long long*)in_bf;
    // flags (NCH*SS ints = 4 KB) after Wo_bf.
    int* flags = (int*)(Wo_bf + (size_t)2 * DD * DD);

    // merged bf16 casts (+ flag zeroing) in one dispatch
    {
        int total = NIN4 + NWI4 + NWO8;            // 4980736, divisible by 256
        cast_all_kernel<<<total / 256, 256, 0, stream>>>(
            (const float4*)inputs, (ushort4*)in_bf,
            (const float4*)Wi,     (ushort4*)Wi_bf,
            Wo,                    Wo_bf,
            flags);
    }

    // GEMM1: u[M, 2D] = in_bf[M, D] @ Wi^T + bi   (bf16 out), N=2048 -> NT=8
    gemm256<DD, 8, 0><<<(M / 256) * 8, 512, 0, stream>>>(
        in_bf, Wi_bf, bi, (void*)u_bf);

    // one-pass scan (u read ONCE; relaxed write-through flag protocol)
    scan_onepass<<<dim3(DD / 256, SS, BB), 256, 0, stream>>>(
        u_bf, plog, Epub, flags, xr_bf);

    // GEMM2: out[M, D] = relu(xr[M, 2D] @ WoP^T + bo)  (f32 out), N=1024 -> NT=4
    gemm256<2 * DD, 4, 1><<<(M / 256) * 4, 512, 0, stream>>>(
        xr_bf, Wo_bf, bo, (void*)out);
}